// Round 8
// baseline (160.507 us; speedup 1.0000x reference)
//
#include <hip/hip_runtime.h>
#include <math.h>

// Geometry: seg_out/logits (2,4,128,128,128) f32, y (2,1,128,128,128) i32,
// calib (20,4) f32, weight scalar int. Output: 1 f32 scalar.
#define VB 2097152            // voxels per (batch, channel) = 128^3
#define QB (VB / 4)           // float4 quads per (batch, channel)
#define NBINS 20

// Accumulation layout (R6 win, extended): every global counter lives on its
// own 128-B cache line, x4 slots by block index -> device-scope atomic RMWs
// spread across many L2 lines; per-address serialization ~256 RMWs even at
// 2048 blocks.
//   float region: 40 accs x 4 slots x PADW words
//   hist  region: 40 u64 cells {true<<32|total} x 4 slots, one line each
#define PADW 32                                   // words per 128-B line
#define SLOTS 4
#define PIDX(i, s) ((((i) * SLOTS) + (s)) * PADW) // word offset of acc i, slot s
#define HBASEW (40 * SLOTS * PADW)                // 5120 words
#define WS_BYTES (2 * 40 * SLOTS * PADW * 4)      // 40960 B

// Privatized LDS histogram: 8 copies, stride 81 words (odd => distinct banks).
#define HCOPIES 8
#define HSTRIDE 81

#define NBLK 2048
#define BPB 1024
#define QSTRIDE (BPB * 256)    // 262144; KITER * QSTRIDE == QB
#define KITER 2

__device__ __forceinline__ float sel(const float4 v, int j) {
    return j == 0 ? v.x : (j == 1 ? v.y : (j == 2 ? v.z : v.w));
}
__device__ __forceinline__ int seli(const int4 v, int j) {
    return j == 0 ? v.x : (j == 1 ? v.y : (j == 2 ? v.z : v.w));
}

__global__ void hybrid_main_k(
        const float* __restrict__ seg, const float* __restrict__ logits,
        const int* __restrict__ y, const int* __restrict__ wt,
        float* __restrict__ ws)
{
    const int b   = blockIdx.x & 1;       // interleave batches across XCDs
    const int blk = blockIdx.x >> 1;      // 0..1023
    const int tid = threadIdx.x;

    __shared__ unsigned int shb[HCOPIES * HSTRIDE];   // 2592 B
    __shared__ float shred[20][4];

    for (int i = tid; i < HCOPIES * HSTRIDE; i += 256) shb[i] = 0u;
    __syncthreads();

    // weight==1 => (1-w)*L2 == 0 exactly; skip the logits stream (uniform,
    // deterministic branch: inputs restored before every launch).
    const bool need2 = (wt[0] != 1);

    const float4* s0 = (const float4*)seg + (size_t)(b * 4 + 0) * QB;
    const float4* s1 = (const float4*)seg + (size_t)(b * 4 + 1) * QB;
    const float4* s2 = (const float4*)seg + (size_t)(b * 4 + 2) * QB;
    const float4* s3 = (const float4*)seg + (size_t)(b * 4 + 3) * QB;
    const int4*   yq = (const int4*)y + (size_t)b * QB;

    // acc[0..3]=Sp, [4..7]=Spt1(one-hot), [8..11]=Cnt1(as float, exact),
    // [12..15]=St2(sigmoid), [16..19]=Spt2
    float acc[20];
    #pragma unroll
    for (int k = 0; k < 20; ++k) acc[k] = 0.0f;

    const float INV_STEP = 20.0f / (1.0f + 1e-8f);
    const int hbase = (tid & (HCOPIES - 1)) * HSTRIDE;
    const int q0 = blk * 256 + tid;

    // ---- software-pipelined loop: prefetch tile k+1 while computing k ----
    float4 cP0 = s0[q0], cP1 = s1[q0], cP2 = s2[q0], cP3 = s3[q0];
    int4   cY  = yq[q0];

    #pragma unroll
    for (int k = 0; k < KITER; ++k) {
        float4 nP0, nP1, nP2, nP3; int4 nY;
        if (k + 1 < KITER) {
            const int q = q0 + (k + 1) * QSTRIDE;
            nP0 = s0[q]; nP1 = s1[q]; nP2 = s2[q]; nP3 = s3[q]; nY = yq[q];
        }
        float4 G0, G1, G2, G3;
        if (need2) {
            const float4* l0 = (const float4*)logits + (size_t)(b * 4 + 0) * QB;
            const float4* l1 = (const float4*)logits + (size_t)(b * 4 + 1) * QB;
            const float4* l2 = (const float4*)logits + (size_t)(b * 4 + 2) * QB;
            const float4* l3 = (const float4*)logits + (size_t)(b * 4 + 3) * QB;
            const int q = q0 + k * QSTRIDE;
            G0 = l0[q]; G1 = l1[q]; G2 = l2[q]; G3 = l3[q];
        }

        #pragma unroll
        for (int j = 0; j < 4; ++j) {
            const float pv0 = sel(cP0, j), pv1 = sel(cP1, j);
            const float pv2 = sel(cP2, j), pv3 = sel(cP3, j);
            const int yj = seli(cY, j);

            acc[0] += pv0; acc[1] += pv1; acc[2] += pv2; acc[3] += pv3;
            acc[4] += (yj == 0) ? pv0 : 0.0f;
            acc[5] += (yj == 1) ? pv1 : 0.0f;
            acc[6] += (yj == 2) ? pv2 : 0.0f;
            acc[7] += (yj == 3) ? pv3 : 0.0f;
            acc[8]  += (yj == 0) ? 1.0f : 0.0f;
            acc[9]  += (yj == 1) ? 1.0f : 0.0f;
            acc[10] += (yj == 2) ? 1.0f : 0.0f;
            acc[11] += (yj == 3) ? 1.0f : 0.0f;

            if (need2) {
                const float sg0 = __fdividef(1.0f, 1.0f + __expf(-sel(G0, j)));
                const float sg1 = __fdividef(1.0f, 1.0f + __expf(-sel(G1, j)));
                const float sg2 = __fdividef(1.0f, 1.0f + __expf(-sel(G2, j)));
                const float sg3 = __fdividef(1.0f, 1.0f + __expf(-sel(G3, j)));
                acc[12] += sg0; acc[13] += sg1; acc[14] += sg2; acc[15] += sg3;
                acc[16] += pv0 * sg0; acc[17] += pv1 * sg1;
                acc[18] += pv2 * sg2; acc[19] += pv3 * sg3;
            }

            // softmax over channels (matches jax.nn.softmax: exp(x-max)/sum)
            const float mx = fmaxf(fmaxf(pv0, pv1), fmaxf(pv2, pv3));
            const float e0 = __expf(pv0 - mx), e1 = __expf(pv1 - mx);
            const float e2 = __expf(pv2 - mx), e3 = __expf(pv3 - mx);
            const float ssum = (e0 + e1) + (e2 + e3);
            const float pr1 = __fdividef(e1, ssum);
            const float pr2 = __fdividef(e2, ssum);
            int b1 = (int)(pr1 * INV_STEP); if (b1 > 19) b1 = 19;
            int b2 = (int)(pr2 * INV_STEP); if (b2 > 19) b2 = 19;
            atomicAdd(&shb[hbase + 20 + b1], 1u);   // class-1 total
            atomicAdd(&shb[hbase + 60 + b2], 1u);   // class-2 total
            if (yj == 1 || yj == 2) {               // mutually exclusive trues
                const int addr = (yj == 1) ? (hbase + b1) : (hbase + 40 + b2);
                atomicAdd(&shb[addr], 1u);
            }
        }
        cP0 = nP0; cP1 = nP1; cP2 = nP2; cP3 = nP3; cY = nY;
    }

    // ---- block reduction (skip the always-zero logits accs when w==1) ----
    const int nred = need2 ? 20 : 12;
    for (int k = 0; k < nred; ++k) {
        float v = acc[k];
        #pragma unroll
        for (int off = 32; off > 0; off >>= 1) v += __shfl_xor(v, off, 64);
        acc[k] = v;
    }
    const int wave = tid >> 6, lane = tid & 63;
    if (lane == 0) {
        for (int k = 0; k < nred; ++k) shred[k][wave] = acc[k];
    }
    __syncthreads();

    // ---- padded, slot-split global accumulation ----
    const int slot = (blockIdx.x >> 1) & (SLOTS - 1);
    if (tid < nred) {
        float t = shred[tid][0] + shred[tid][1] + shred[tid][2] + shred[tid][3];
        atomicAdd(&ws[PIDX(b * 20 + tid, slot)], t);
    }
    // histogram: pack {true, total} for one (class, bin) into one u64 atomic.
    if (tid < 40) {
        const int cc = tid / 20, k = tid % 20;
        unsigned int vt = 0, vn = 0;
        #pragma unroll
        for (int c = 0; c < HCOPIES; ++c) {
            vt += shb[c * HSTRIDE + cc * 40 + k];
            vn += shb[c * HSTRIDE + cc * 40 + 20 + k];
        }
        const unsigned long long pk = ((unsigned long long)vt << 32) | vn;
        if (pk) {
            unsigned long long* h =
                (unsigned long long*)(ws + HBASEW) + (size_t)(tid * SLOTS + slot) * (PADW / 2);
            atomicAdd(h, pk);
        }
    }
}

__device__ __forceinline__ float fsigmoid(float x) {
    return __fdividef(1.0f, 1.0f + __expf(-x));
}

__device__ double dice_term(const double Sp[2], const double St[2], const double Spt[2],
                            double w0, double w1)
{
    const double sumP = Sp[0] + Sp[1], sumT = St[0] + St[1];
    const double u1 = sumP + sumT;
    const double u0 = (2.0 * (double)VB - sumP) + (2.0 * (double)VB - sumT);
    const double uni = w0 * u0 + w1 * u1;
    double dsum = 0.0;
    for (int b = 0; b < 2; ++b) {
        const double i1 = Spt[b];
        const double i0 = (double)VB - Sp[b] - St[b] + Spt[b];
        const double inter = w0 * i0 + w1 * i1;
        double dice = (2.0 * inter + 1.0) / (uni + 1.0);
        if (isnan(dice)) dice = 1.0;
        dsum += dice;
    }
    return 1.0 - 0.5 * dsum;
}

__device__ __forceinline__ float rd_acc(const float* ws, int i) {
    float s = 0.0f;
    #pragma unroll
    for (int k = 0; k < SLOTS; ++k) s += ws[PIDX(i, k)];
    return s;
}

__global__ void finalize_k(const float* __restrict__ ws,
                           const float* __restrict__ calib,
                           const int* __restrict__ wt,
                           float* __restrict__ out)
{
    const int t = threadIdx.x;

    // ECE terms in parallel: lanes 0..39 each handle one (class, bin) cell.
    float term = 0.0f;
    if (t < 40) {
        const unsigned long long* h = (const unsigned long long*)(ws + HBASEW);
        unsigned long long v = 0;
        #pragma unroll
        for (int s = 0; s < SLOTS; ++s)
            v += h[(size_t)(t * SLOTS + s) * (PADW / 2)];
        const unsigned int vt = (unsigned int)(v >> 32);
        const unsigned int vn = (unsigned int)v;
        const int cc = t / NBINS, k = t % NBINS;
        const float bt   = fsigmoid((float)vt);
        const float btot = fsigmoid((float)vn);
        const float cal  = fsigmoid(calib[k * 4 + (cc + 1)]);
        const float d = cal - __fdividef(bt, btot);
        term = d * d;
    }
    #pragma unroll
    for (int off = 32; off > 0; off >>= 1) term += __shfl_xor(term, off, 64);

    if (t == 0) {
        const double means[4] = {0.03, 0.02, 0.01, 0.01};
        double L1 = 0.0, L2 = 0.0;
        for (int c = 0; c < 4; ++c) {
            const double mean = means[c];
            const double w1 = 1.0 / (mean * mean);
            const double w0 = 1.0 / ((1.0 - mean) * (1.0 - mean));
            double Sp[2], Spt1[2], C1[2], St2[2], Spt2[2];
            for (int b = 0; b < 2; ++b) {
                Sp[b]   = (double)rd_acc(ws, b * 20 + 0 + c);
                Spt1[b] = (double)rd_acc(ws, b * 20 + 4 + c);
                C1[b]   = (double)rd_acc(ws, b * 20 + 8 + c);
                St2[b]  = (double)rd_acc(ws, b * 20 + 12 + c);
                Spt2[b] = (double)rd_acc(ws, b * 20 + 16 + c);
            }
            L1 += dice_term(Sp, C1, Spt1, w0, w1);
            L2 += dice_term(Sp, St2, Spt2, w0, w1);
        }
        L1 *= 0.2; L2 *= 0.2;   // sum of 4 channel losses / 5.0
        const double w = (double)wt[0];
        const double ece = (double)term / (double)NBINS;
        out[0] = (float)(w * L1 + (1.0 - w) * L2 + ece);
    }
}

extern "C" void kernel_launch(void* const* d_in, const int* in_sizes, int n_in,
                              void* d_out, int out_size, void* d_ws, size_t ws_size,
                              hipStream_t stream)
{
    const float* seg    = (const float*)d_in[0];
    const float* calib  = (const float*)d_in[1];
    const float* logits = (const float*)d_in[2];
    const int*   y      = (const int*)d_in[3];
    const int*   wt     = (const int*)d_in[4];
    float* ws  = (float*)d_ws;
    float* out = (float*)d_out;

    hipMemsetAsync(ws, 0, WS_BYTES, stream);
    hipLaunchKernelGGL(hybrid_main_k, dim3(NBLK), dim3(256), 0, stream,
                       seg, logits, y, wt, ws);
    hipLaunchKernelGGL(finalize_k, dim3(1), dim3(64), 0, stream, ws, calib, wt, out);
}